// Round 18
// baseline (403.947 us; speedup 1.0000x reference)
//
#include <hip/hip_runtime.h>
#include <hip/hip_bf16.h>
#include <hip/hip_fp16.h>

#define E4M3_MAX 240.0f

typedef __attribute__((ext_vector_type(8))) __bf16 bf16x8;
typedef __attribute__((ext_vector_type(16))) float f32x16;
typedef unsigned short ushort_t;

__device__ __forceinline__ void gload_lds16(const void* g, void* l) {
  __builtin_amdgcn_global_load_lds(
      (const __attribute__((address_space(1))) void*)g,
      (__attribute__((address_space(3))) void*)l,
      16, 0, 0);
}

// ---------------- amax over |weight| ----------------
__global__ void amax_abs_kernel(const float* __restrict__ w, int n4,
                                unsigned* __restrict__ amax_bits) {
  float m = 0.0f;
  const float4* w4 = (const float4*)w;
  int stride = gridDim.x * blockDim.x;
  for (int i = blockIdx.x * blockDim.x + threadIdx.x; i < n4; i += stride) {
    float4 v = w4[i];
    m = fmaxf(m, fmaxf(fmaxf(fabsf(v.x), fabsf(v.y)),
                       fmaxf(fabsf(v.z), fabsf(v.w))));
  }
  for (int off = 32; off > 0; off >>= 1)
    m = fmaxf(m, __shfl_down(m, off, 64));
  __shared__ float smax[4];
  int l = threadIdx.x & 63, wv = threadIdx.x >> 6;
  if (l == 0) smax[wv] = m;
  __syncthreads();
  if (threadIdx.x == 0) {
    float bm = fmaxf(fmaxf(smax[0], smax[1]), fmaxf(smax[2], smax[3]));
    atomicMax(amax_bits, __float_as_uint(bm));
  }
}

// ---- fused: quantize weight -> bf16 qw, then convert x -> bf16 xb ----
__global__ void prep_kernel(const float* __restrict__ w,
                            const unsigned* __restrict__ amax_bits,
                            ushort_t* __restrict__ qw, int nw4,
                            const float* __restrict__ x,
                            ushort_t* __restrict__ xb, int nx4) {
  float amax = __uint_as_float(*amax_bits);
  float scale = fmaxf(amax / E4M3_MAX, 1e-10f);
  float inv_scale = 1.0f / scale;
  int stride = gridDim.x * blockDim.x;
  int tid0 = blockIdx.x * blockDim.x + threadIdx.x;

  const float4* w4 = (const float4*)w;
  ushort4* q4 = (ushort4*)qw;
  for (int i = tid0; i < nw4; i += stride) {
    float4 v = w4[i];
    float r[4] = {v.x, v.y, v.z, v.w};
    ushort_t o[4];
#pragma unroll
    for (int j = 0; j < 4; ++j) {
      float s = fminf(fmaxf(r[j] * inv_scale, -E4M3_MAX), E4M3_MAX);
      s = __half2float(__float2half(s));   // fp16 round-trip (RNE)
      float q = rintf(s * 8.0f) * 0.125f;  // mantissa grid, half-to-even
      q = fminf(fmaxf(q, -E4M3_MAX), E4M3_MAX);
      __hip_bfloat16 h = __float2bfloat16(q * scale);
      o[j] = *(ushort_t*)&h;
    }
    ushort4 ov = {o[0], o[1], o[2], o[3]};
    q4[i] = ov;
  }

  const float4* x4 = (const float4*)x;
  ushort4* o4 = (ushort4*)xb;
  for (int i = tid0; i < nx4; i += stride) {
    float4 v = x4[i];
    __hip_bfloat16 h0 = __float2bfloat16(v.x);
    __hip_bfloat16 h1 = __float2bfloat16(v.y);
    __hip_bfloat16 h2 = __float2bfloat16(v.z);
    __hip_bfloat16 h3 = __float2bfloat16(v.w);
    ushort4 o = {*(ushort_t*)&h0, *(ushort_t*)&h1,
                 *(ushort_t*)&h2, *(ushort_t*)&h3};
    o4[i] = o;
  }
}

// == 128x256 bf16 GEMM — 32x32x16, BK=32, 48KB LDS, 2 blocks/CU (VGPR-feasible) ==
// C = A * Bt^T + bias.  A: [8192][4096] bf16, Bt: [4096][4096] bf16, C fp32.
// 8 waves (2M x 4N), per wave 64x64 -> acc = 4 x f32x16 = 64 VGPR; total ~120
// fits launch_bounds(512,4)'s 128-VGPR cap (R16's failure was acc=128 alone).
// Per K32-tile (R7 sync discipline): P1: 8 ds_reads; BAR; LGKM0; 4 MFMA; BAR.
// P2: stage A,B(t+2)->cb (3 gloads; cb's reads certified by P1-end BAR); BAR;
// 4 MFMA; VMC3 (never 0 — keeps newest 3 in flight, drains t+1's 3, staged 3
// phases ago); BAR.  Two independent blocks per SIMD cover each other's
// sync/DS stalls (m114) — the axis R13 (VMC0+fetch-confounded) and R16
// (VGPR-infeasible) never cleanly tested.

#define BAR() do { asm volatile("" ::: "memory"); \
                   __builtin_amdgcn_s_barrier(); \
                   asm volatile("" ::: "memory"); } while (0)
#define LGKM0() asm volatile("s_waitcnt lgkmcnt(0)" ::: "memory")
#define VMC3() asm volatile("s_waitcnt vmcnt(3)" ::: "memory")
#define VMC0() asm volatile("s_waitcnt vmcnt(0)" ::: "memory")
#define NOVM() do {} while (0)

__global__ __launch_bounds__(512, 4) void gemm128x256(
    const ushort_t* __restrict__ A, const ushort_t* __restrict__ Bt,
    const float* __restrict__ bias, float* __restrict__ C) {
  constexpr int K = 4096, N = 4096;
  // As: [buf][128 rows x 32 cols] = 8 KB/buf; Bs: [buf][256 x 32] = 16 KB/buf
  __shared__ __align__(16) ushort_t As[2][4096];
  __shared__ __align__(16) ushort_t Bs[2][8192];

  const int tid = threadIdx.x;
  const int wid = tid >> 6, lane = tid & 63;
  const int wm = wid >> 2, wn = wid & 3;     // 2 x 4 wave grid (64x64 each)
  const int l31 = lane & 31, lk2 = lane >> 5;

  // XCD swizzle (nwg = 1024, divisible by 8)
  int bid = blockIdx.x;
  int swz = (bid & 7) * 128 + (bid >> 3);
  int bm = swz >> 4, bn = swz & 15;          // bm 0..63, bn 0..15

  const ushort_t* Ab = A + (size_t)bm * 128 * K;
  const ushort_t* Bb = Bt + (size_t)bn * 256 * K;

  // staging (σ2-swizzled source, linear LDS dest — R13/R16-verified 0-conflict):
  // A: slot s = tid; row = s>>2; granule c = (s&3)^σ2(row), σ2(r)=(r&3)^((r>>2)&3)
  const int rowA = tid >> 2;
  const int offA = rowA * K + (((tid & 3) ^ (rowA & 3) ^ ((rowA >> 2) & 3))) * 8;
  int offB[2];
#pragma unroll
  for (int q = 0; q < 2; ++q) {
    int s = q * 512 + tid;
    int row = s >> 2;
    offB[q] = row * K + ((s & 3) ^ (row & 3) ^ ((row >> 2) & 3)) * 8;
  }

  // stage one full K32 tile: A (1 gload/thread) + B (2 gloads/thread)
#define STAGE(buf, kt)                                                     \
  do {                                                                     \
    gload_lds16(Ab + (size_t)(kt) * 32 + offA, &As[buf][(wid * 64) * 8]);  \
    _Pragma("unroll") for (int q = 0; q < 2; ++q)                          \
      gload_lds16(Bb + (size_t)(kt) * 32 + offB[q],                        \
                  &Bs[buf][(q * 512 + wid * 64) * 8]);                     \
  } while (0)

  // swizzled ds_read: granule = (ks*2 + lk2) ^ σ2(row); row bases (wm*64,
  // wn*64, rg*32, cg*32) are multiples of 32 -> σ2(row) is lane-constant.
  const int sig2 = (l31 & 3) ^ ((l31 >> 2) & 3);
  int xk2[2];
#pragma unroll
  for (int ks = 0; ks < 2; ++ks) xk2[ks] = ((ks * 2 + lk2) ^ sig2) * 8;

  bf16x8 af[2][2], bf[2][2];
  f32x16 acc[2][2] = {};

#define RD8(cb)                                                            \
  do {                                                                     \
    _Pragma("unroll") for (int cg = 0; cg < 2; ++cg)                       \
      _Pragma("unroll") for (int ks = 0; ks < 2; ++ks)                     \
        bf[cg][ks] = *(const bf16x8*)                                      \
            &Bs[cb][(wn * 64 + cg * 32 + l31) * 32 + xk2[ks]];             \
    _Pragma("unroll") for (int rg = 0; rg < 2; ++rg)                       \
      _Pragma("unroll") for (int ks = 0; ks < 2; ++ks)                     \
        af[rg][ks] = *(const bf16x8*)                                      \
            &As[cb][(wm * 64 + (rg) * 32 + l31) * 32 + xk2[ks]];           \
  } while (0)

  // 4 MFMA: one row-group x both col-groups x K=32
#define MMA4(rg)                                                           \
  do { _Pragma("unroll") for (int ks = 0; ks < 2; ++ks) {                  \
    acc[rg][0] = __builtin_amdgcn_mfma_f32_32x32x16_bf16(                  \
        af[rg][ks], bf[0][ks], acc[rg][0], 0, 0, 0);                       \
    acc[rg][1] = __builtin_amdgcn_mfma_f32_32x32x16_bf16(                  \
        af[rg][ks], bf[1][ks], acc[rg][1], 0, 0, 0);                       \
  } } while (0)

  // One K32-tile, 2 phases (R7 discipline), VMC3 never-drain.
#define TILE(cb, t, DO_S, VMCX)                                            \
  do {                                                                     \
    RD8(cb);                                                               \
    BAR(); LGKM0();                                                        \
    __builtin_amdgcn_s_setprio(1); MMA4(0);                                \
    __builtin_amdgcn_s_setprio(0); BAR();                                  \
    if (DO_S) STAGE(cb, (t) + 2);                                          \
    BAR();                                                                 \
    __builtin_amdgcn_s_setprio(1); MMA4(1);                                \
    __builtin_amdgcn_s_setprio(0); VMCX; BAR();                            \
  } while (0)

  // ---- prologue: stage tiles 0 (buf0) and 1 (buf1) ----
  STAGE(0, 0);
  STAGE(1, 1);
  VMC3();   // retire tile 0's 3 loads; tile 1's 3 stay in flight
  BAR();

  // ---- main loop: 128 K32-tiles; tile t's stage targets its own buf ----
  for (int t = 0; t < 126; t += 2) {
    TILE(0, t, 1, VMC3());
    TILE(1, t + 1, 1, VMC3());
  }
  // t=124/125 staged tiles 126,127.
  TILE(0, 126, 0, VMC0());   // drain tile 127's 3 loads
  TILE(1, 127, 0, NOVM());

  // ---- C write + bias (32x32 D: col = lane&31, row = (r&3)+8*(r>>2)+4*(lane>>5)) ----
  float* Cb = C + (size_t)(bm * 128 + wm * 64) * N + bn * 256 + wn * 64;
#pragma unroll
  for (int cg = 0; cg < 2; ++cg) {
    int n = cg * 32 + l31;
    float bv = bias[bn * 256 + wn * 64 + n];
#pragma unroll
    for (int rg = 0; rg < 2; ++rg) {
#pragma unroll
      for (int r = 0; r < 16; ++r) {
        int row = rg * 32 + (r & 3) + 8 * (r >> 2) + 4 * lk2;
        Cb[(size_t)row * N + n] = acc[rg][cg][r] + bv;
      }
    }
  }
}

extern "C" void kernel_launch(void* const* d_in, const int* in_sizes, int n_in,
                              void* d_out, int out_size, void* d_ws, size_t ws_size,
                              hipStream_t stream) {
  const float* x = (const float*)d_in[0];     // [4,2048,4096] fp32
  const float* wt = (const float*)d_in[1];    // [4096,4096] fp32
  const float* bias = (const float*)d_in[2];  // [4096] fp32
  float* out = (float*)d_out;                 // [4,2048,4096] fp32

  const int DIN = 4096;
  const int NW = in_sizes[1];                 // 16777216
  const int M = in_sizes[0] / DIN;            // 8192

  char* ws = (char*)d_ws;
  unsigned* amax_bits = (unsigned*)ws;
  ushort_t* qw = (ushort_t*)(ws + 256);                    // bf16 [4096][4096]
  ushort_t* xb = (ushort_t*)(ws + 256 + (size_t)NW * 2);   // bf16 [8192][4096]

  hipMemsetAsync(amax_bits, 0, 4, stream);
  hipLaunchKernelGGL(amax_abs_kernel, dim3(1024), dim3(256), 0, stream,
                     wt, NW / 4, amax_bits);
  hipLaunchKernelGGL(prep_kernel, dim3(2048), dim3(256), 0, stream,
                     wt, amax_bits, qw, NW / 4, x, xb, (M * DIN) / 4);

  // (8192/128) x (4096/256) = 64 x 16 = 1024 blocks of 512 threads
  hipLaunchKernelGGL(gemm128x256, dim3(1024), dim3(512), 0, stream,
                     xb, qw, bias, out);
}

// Round 19
// 325.372 us; speedup vs baseline: 1.2415x; 1.2415x over previous
//
#include <hip/hip_runtime.h>
#include <hip/hip_bf16.h>
#include <hip/hip_fp16.h>

#define E4M3_MAX 240.0f

typedef __attribute__((ext_vector_type(8))) __bf16 bf16x8;
typedef __attribute__((ext_vector_type(16))) float f32x16;
typedef unsigned short ushort_t;

__device__ __forceinline__ void gload_lds16(const void* g, void* l) {
  __builtin_amdgcn_global_load_lds(
      (const __attribute__((address_space(1))) void*)g,
      (__attribute__((address_space(3))) void*)l,
      16, 0, 0);
}

// ---------------- amax over |weight| ----------------
__global__ void amax_abs_kernel(const float* __restrict__ w, int n4,
                                unsigned* __restrict__ amax_bits) {
  float m = 0.0f;
  const float4* w4 = (const float4*)w;
  int stride = gridDim.x * blockDim.x;
  for (int i = blockIdx.x * blockDim.x + threadIdx.x; i < n4; i += stride) {
    float4 v = w4[i];
    m = fmaxf(m, fmaxf(fmaxf(fabsf(v.x), fabsf(v.y)),
                       fmaxf(fabsf(v.z), fabsf(v.w))));
  }
  for (int off = 32; off > 0; off >>= 1)
    m = fmaxf(m, __shfl_down(m, off, 64));
  __shared__ float smax[4];
  int l = threadIdx.x & 63, wv = threadIdx.x >> 6;
  if (l == 0) smax[wv] = m;
  __syncthreads();
  if (threadIdx.x == 0) {
    float bm = fmaxf(fmaxf(smax[0], smax[1]), fmaxf(smax[2], smax[3]));
    atomicMax(amax_bits, __float_as_uint(bm));
  }
}

// ---- fused: quantize weight -> bf16 qw, then convert x -> bf16 xb ----
__global__ void prep_kernel(const float* __restrict__ w,
                            const unsigned* __restrict__ amax_bits,
                            ushort_t* __restrict__ qw, int nw4,
                            const float* __restrict__ x,
                            ushort_t* __restrict__ xb, int nx4) {
  float amax = __uint_as_float(*amax_bits);
  float scale = fmaxf(amax / E4M3_MAX, 1e-10f);
  float inv_scale = 1.0f / scale;
  int stride = gridDim.x * blockDim.x;
  int tid0 = blockIdx.x * blockDim.x + threadIdx.x;

  const float4* w4 = (const float4*)w;
  ushort4* q4 = (ushort4*)qw;
  for (int i = tid0; i < nw4; i += stride) {
    float4 v = w4[i];
    float r[4] = {v.x, v.y, v.z, v.w};
    ushort_t o[4];
#pragma unroll
    for (int j = 0; j < 4; ++j) {
      float s = fminf(fmaxf(r[j] * inv_scale, -E4M3_MAX), E4M3_MAX);
      s = __half2float(__float2half(s));   // fp16 round-trip (RNE)
      float q = rintf(s * 8.0f) * 0.125f;  // mantissa grid, half-to-even
      q = fminf(fmaxf(q, -E4M3_MAX), E4M3_MAX);
      __hip_bfloat16 h = __float2bfloat16(q * scale);
      o[j] = *(ushort_t*)&h;
    }
    ushort4 ov = {o[0], o[1], o[2], o[3]};
    q4[i] = ov;
  }

  const float4* x4 = (const float4*)x;
  ushort4* o4 = (ushort4*)xb;
  for (int i = tid0; i < nx4; i += stride) {
    float4 v = x4[i];
    __hip_bfloat16 h0 = __float2bfloat16(v.x);
    __hip_bfloat16 h1 = __float2bfloat16(v.y);
    __hip_bfloat16 h2 = __float2bfloat16(v.z);
    __hip_bfloat16 h3 = __float2bfloat16(v.w);
    ushort4 o = {*(ushort_t*)&h0, *(ushort_t*)&h1,
                 *(ushort_t*)&h2, *(ushort_t*)&h3};
    o4[i] = o;
  }
}

// ============ 256x256 8-phase bf16 GEMM — 32x32x16 MFMA, σ-swizzle (R7) ============
// C = A * Bt^T + bias.  A: [8192][4096] bf16, Bt: [4096][4096] bf16, C fp32.
// 8 waves (2M x 4N), BK=64, dbuf LDS 128 KiB.  R2 phase/stage/vmcnt skeleton:
// reads 12/12/0/0 per K-tile (front-loaded; P3/P4 pure-MFMA), stages
// B(t+1)@P1-2, A(t+2)@P3-4, B(t+2)@P5-6, A(t+3)@P7-8, vmcnt(4)@P4/P8 (never 0
// in steady state).  Swizzle σ(r) = (r&7)^((r>>3)&3): conflict-free (measured 0).
// FINAL: best of 11 structural variants over 18 rounds (267-271 µs GEMM,
// 46.6-47.5% MfmaUtil, 1031 TF).  Axes closed by measurement:
//  - schedule: R3/R4/R5/R8/R9/R10/R11/R12/R14 all -5..-33% vs this skeleton
//  - occupancy: 2 blocks/CU resident (R18, 42% occ) but DS-pipe shared ->
//    3072 cyc DS floor > 2065 MFMA floor; 128-tile doubles FETCH (R13/R18)
//  - VGPR: 256² needs acc=128 VGPR -> launch_bounds(512,2) mandatory (R16)

#define BAR() do { asm volatile("" ::: "memory"); \
                   __builtin_amdgcn_s_barrier(); \
                   asm volatile("" ::: "memory"); } while (0)
#define LGKM0() asm volatile("s_waitcnt lgkmcnt(0)" ::: "memory")
#define LGKM8() asm volatile("s_waitcnt lgkmcnt(8)" ::: "memory")
#define VMC4() asm volatile("s_waitcnt vmcnt(4)" ::: "memory")
#define VMC0() asm volatile("s_waitcnt vmcnt(0)" ::: "memory")
#define NOVM() do {} while (0)

__global__ __launch_bounds__(512, 2) void gemm256_w32(
    const ushort_t* __restrict__ A, const ushort_t* __restrict__ Bt,
    const float* __restrict__ bias, float* __restrict__ C) {
  constexpr int K = 4096, N = 4096;
  __shared__ __align__(16) ushort_t As[2][2][8192];
  __shared__ __align__(16) ushort_t Bs[2][2][8192];

  const int tid = threadIdx.x;
  const int wid = tid >> 6, lane = tid & 63;
  const int wm = wid >> 2, wn = wid & 3;     // 2 x 4 wave grid
  const int l31 = lane & 31, lk2 = lane >> 5;

  // XCD swizzle (nwg = 512, divisible by 8)
  int bid = blockIdx.x;
  int swz = (bid & 7) * 64 + (bid >> 3);
  int bm = swz >> 4, bn = swz & 15;          // nbn = 16

  const ushort_t* Ab = A + (size_t)bm * 256 * K;
  const ushort_t* Bb = Bt + (size_t)bn * 256 * K;

  // staging: slot s = q*512+tid; row = s>>3; granule c = (s&7) ^ σ(row),
  // σ(r) = (r&7) ^ ((r>>3)&3)
  int offG[2];
#pragma unroll
  for (int q = 0; q < 2; ++q) {
    int s = q * 512 + tid;
    int row = s >> 3;
    int c = (s & 7) ^ (row & 7) ^ ((row >> 3) & 3);
    offG[q] = row * K + c * 8;
  }

  // stage ONE half-tile (2 loads/thread)
#define STAGE_AH(buf, kt, h)                                               \
  do { _Pragma("unroll") for (int q = 0; q < 2; ++q)                       \
    gload_lds16(Ab + (size_t)(h) * 128 * K + (kt) * 64 + offG[q],          \
                &As[buf][h][(q * 512 + wid * 64) * 8]); } while (0)
#define STAGE_BH(buf, kt, h)                                               \
  do { _Pragma("unroll") for (int q = 0; q < 2; ++q)                       \
    gload_lds16(Bb + (size_t)(h) * 128 * K + (kt) * 64 + offG[q],          \
                &Bs[buf][h][(q * 512 + wid * 64) * 8]); } while (0)

  // swizzled ds_read: granule = (ks*2 + lk2) ^ σ(row); row-group offsets are
  // multiples of 32 so σ(row) = (l31&7) ^ ((l31>>3)&3) is a lane constant.
  const int bhalf = wn >> 1;
  const int brow0 = (wn & 1) * 64;
  const int sig = (l31 & 7) ^ ((l31 >> 3) & 3);
  int xks[4];
#pragma unroll
  for (int ks = 0; ks < 4; ++ks) xks[ks] = ((ks * 2 + lk2) ^ sig) * 8;

  bf16x8 af[4][4], bf[2][4];
  f32x16 acc[4][2] = {};

#define RD_A32(buf, rg)                                                    \
  do { _Pragma("unroll") for (int ks = 0; ks < 4; ++ks)                    \
    af[rg][ks] = *(const bf16x8*)                                          \
        &As[buf][wm][((rg) * 32 + l31) * 64 + xks[ks]]; } while (0)
#define RD_B32(buf)                                                        \
  do { _Pragma("unroll") for (int cg = 0; cg < 2; ++cg)                    \
    _Pragma("unroll") for (int ks = 0; ks < 4; ++ks)                       \
      bf[cg][ks] = *(const bf16x8*)                                        \
          &Bs[buf][bhalf][(brow0 + cg * 32 + l31) * 64 + xks[ks]]; } while (0)

  // 8 MFMA of 32x32x16: one row-group (32 C-rows) x both col-groups x K=64
#define MMA8(rg)                                                           \
  do { __builtin_amdgcn_s_setprio(1);                                      \
    _Pragma("unroll") for (int ks = 0; ks < 4; ++ks) {                     \
      acc[rg][0] = __builtin_amdgcn_mfma_f32_32x32x16_bf16(                \
          af[rg][ks], bf[0][ks], acc[rg][0], 0, 0, 0);                     \
      acc[rg][1] = __builtin_amdgcn_mfma_f32_32x32x16_bf16(                \
          af[rg][ks], bf[1][ks], acc[rg][1], 0, 0, 0);                     \
    }                                                                      \
    __builtin_amdgcn_s_setprio(0); } while (0)

  // One iteration = 2 K-tiles (t in buf0, t+1 in buf1), 8 phases (R2 skeleton).
#define ITER(t, SB1, SA2, SB2, SA3, VM4, VM8)                              \
  do {                                                                     \
    RD_B32(0); RD_A32(0, 0);                                               \
    if (SB1) STAGE_BH(1, (t) + 1, 0);                                      \
    LGKM8(); BAR(); LGKM0(); MMA8(0); BAR();                               \
    RD_A32(0, 1); RD_A32(0, 2); RD_A32(0, 3);                              \
    if (SB1) STAGE_BH(1, (t) + 1, 1);                                      \
    LGKM8(); BAR(); LGKM0(); MMA8(1); BAR();                               \
    if (SA2) STAGE_AH(0, (t) + 2, 0);                                      \
    BAR(); MMA8(2); BAR();                                                 \
    if (SA2) STAGE_AH(0, (t) + 2, 1);                                      \
    BAR(); MMA8(3); VM4; BAR();                                            \
    RD_B32(1); RD_A32(1, 0);                                               \
    if (SB2) STAGE_BH(0, (t) + 2, 0);                                      \
    LGKM8(); BAR(); LGKM0(); MMA8(0); BAR();                               \
    RD_A32(1, 1); RD_A32(1, 2); RD_A32(1, 3);                              \
    if (SB2) STAGE_BH(0, (t) + 2, 1);                                      \
    LGKM8(); BAR(); LGKM0(); MMA8(1); BAR();                               \
    if (SA3) STAGE_AH(1, (t) + 3, 0);                                      \
    BAR(); MMA8(2); BAR();                                                 \
    if (SA3) STAGE_AH(1, (t) + 3, 1);                                      \
    BAR(); MMA8(3); VM8; BAR();                                            \
  } while (0)

  // ---- prologue: tile0 (A,B) + A(1); A(1)'s 4 loads stay in flight ----
  STAGE_AH(0, 0, 0); STAGE_AH(0, 0, 1);
  STAGE_BH(0, 0, 0); STAGE_BH(0, 0, 1);
  STAGE_AH(1, 1, 0); STAGE_AH(1, 1, 1);
  VMC4();
  BAR();

  // ---- main loop: tiles 0..61 ----
  for (int t = 0; t < 62; t += 2)
    ITER(t, 1, 1, 1, 1, VMC4(), VMC4());
  // t=60 stages B(61), A(62), B(62), A(63) — all in range.

  // ---- peeled final iteration: tiles 62,63 (stage B(63) only) ----
  ITER(62, 1, 0, 0, 0, VMC0(), NOVM());

  // ---- C write + bias (32x32 D: col = lane&31, row = (r&3)+8*(r>>2)+4*(lane>>5)) ----
  float* Cb = C + (size_t)(bm * 256 + wm * 128) * N + bn * 256 + wn * 64;
#pragma unroll
  for (int cg = 0; cg < 2; ++cg) {
    int n = cg * 32 + l31;
    float bv = bias[bn * 256 + wn * 64 + n];
#pragma unroll
    for (int rg = 0; rg < 4; ++rg) {
#pragma unroll
      for (int r = 0; r < 16; ++r) {
        int row = rg * 32 + (r & 3) + 8 * (r >> 2) + 4 * lk2;
        Cb[(size_t)row * N + n] = acc[rg][cg][r] + bv;
      }
    }
  }
}

extern "C" void kernel_launch(void* const* d_in, const int* in_sizes, int n_in,
                              void* d_out, int out_size, void* d_ws, size_t ws_size,
                              hipStream_t stream) {
  const float* x = (const float*)d_in[0];     // [4,2048,4096] fp32
  const float* wt = (const float*)d_in[1];    // [4096,4096] fp32
  const float* bias = (const float*)d_in[2];  // [4096] fp32
  float* out = (float*)d_out;                 // [4,2048,4096] fp32

  const int DIN = 4096;
  const int NW = in_sizes[1];                 // 16777216
  const int M = in_sizes[0] / DIN;            // 8192

  char* ws = (char*)d_ws;
  unsigned* amax_bits = (unsigned*)ws;
  ushort_t* qw = (ushort_t*)(ws + 256);                    // bf16 [4096][4096]
  ushort_t* xb = (ushort_t*)(ws + 256 + (size_t)NW * 2);   // bf16 [8192][4096]

  hipMemsetAsync(amax_bits, 0, 4, stream);
  hipLaunchKernelGGL(amax_abs_kernel, dim3(1024), dim3(256), 0, stream,
                     wt, NW / 4, amax_bits);
  hipLaunchKernelGGL(prep_kernel, dim3(2048), dim3(256), 0, stream,
                     wt, amax_bits, qw, NW / 4, x, xb, (M * DIN) / 4);

  hipLaunchKernelGGL(gemm256_w32, dim3(512), dim3(512), 0, stream,
                     xb, qw, bias, out);
}